// Round 2
// baseline (284.627 us; speedup 1.0000x reference)
//
#include <hip/hip_runtime.h>
#include <math.h>

// softIoULoss: out = 1 - (I + 1) / (M + (nc+1)*S - I + 1)
//   I = sum(sigmoid(0.5 - |x-t|) * matched)
//   M = sum(matched),  S = sum(sigmoid(0.5 - |x-t|))
//   matched = (t == floor(t)) && (t >= 0) && (t <= nc)
//
// R8 post-mortem: PAIRS=4 + 8 waves/SIMD + resident grid was NEUTRAL
// (257.1 vs 260.0) -> occupancy was not the limiter. Either effective
// read BW is capped (~3.3-3.6 TB/s) by something insensitive to wave
// count/ILP depth, or the kernel is already at the ~43us read floor and
// the bench is reset-dominated (top-5 all 79us harness fills).
// R9: single-variable A/B — drop the NT flag (never tested; the 6.3 TB/s
// copy ceiling uses PLAIN dwordx4 loads). Everything else identical to R8.
// Predict: NT-capped -> bench ~228-235; neutral -> kernel is at the HBM
// floor and next round is <<ROOFLINE>>.

#define BLOCK 256
#define PAIRS 4      // float4-pairs per thread per round (32 data VGPRs)
#define FULLGRID 2048   // 8 blocks/CU x 256 CU -> 32 waves/CU resident
#define MAXGRID 16384   // workspace partial-array spacing (ws layout fixed)

typedef float f4_t __attribute__((ext_vector_type(4)));

__device__ __forceinline__ void accum4(f4_t xv, f4_t tv, float ncf,
                                       float& s_inter, float& s_match, float& s_sig) {
#pragma unroll
    for (int j = 0; j < 4; ++j) {
        float tt = tv[j];
        float z  = 0.5f - fabsf(xv[j] - tt);
        float sg = __builtin_amdgcn_rcpf(1.0f + __expf(-z));
        float m  = (tt == floorf(tt) && tt >= 0.f && tt <= ncf) ? 1.f : 0.f;
        s_sig   += sg;
        s_match += m;
        s_inter += sg * m;
    }
}

__global__ __launch_bounds__(BLOCK, 8) void soft_iou_partial(
    const float* __restrict__ x,
    const float* __restrict__ t,
    const int* __restrict__ ncls_p,
    float* __restrict__ pI,     // [gridDim.x]
    float* __restrict__ pM,     // [gridDim.x]
    float* __restrict__ pS,     // [gridDim.x]
    int n)
{
    const int tid = threadIdx.x;
    const long long nthreads = (long long)gridDim.x * BLOCK;
    const long long gtid     = (long long)blockIdx.x * BLOCK + tid;

    const float ncf = (float)(*ncls_p);

    float s_inter = 0.f, s_match = 0.f, s_sig = 0.f;

    const long long nvec = (long long)n >> 2;   // float4 count
    const f4_t* __restrict__ x4 = (const f4_t*)x;
    const f4_t* __restrict__ t4 = (const f4_t*)t;

    const long long step = (long long)PAIRS * nthreads;
    long long i = gtid;
    // grid-stride rounds: 2*PAIRS independent PLAIN dwordx4 loads per round
    // (R9 A/B: NT flag removed), x/t interleaved; no sched_barrier so the
    // compiler may hoist the next round's loads under this round's compute.
    for (; i + (PAIRS - 1) * nthreads < nvec; i += step) {
        f4_t xv[PAIRS], tv[PAIRS];
#pragma unroll
        for (int k = 0; k < PAIRS; ++k) {
            xv[k] = x4[i + (long long)k * nthreads];
            tv[k] = t4[i + (long long)k * nthreads];
        }
#pragma unroll
        for (int k = 0; k < PAIRS; ++k)
            accum4(xv[k], tv[k], ncf, s_inter, s_match, s_sig);
    }
    // remaining full float4s
    for (; i < nvec; i += nthreads) {
        accum4(x4[i], t4[i], ncf, s_inter, s_match, s_sig);
    }
    // scalar tail (n % 4)
    for (long long k = (nvec << 2) + gtid; k < n; k += nthreads) {
        float tt = t[k];
        float z  = 0.5f - fabsf(x[k] - tt);
        float sg = __builtin_amdgcn_rcpf(1.0f + __expf(-z));
        float m  = (tt == floorf(tt) && tt >= 0.f && tt <= ncf) ? 1.f : 0.f;
        s_sig += sg; s_match += m; s_inter += sg * m;
    }

    // wave (64-lane) reduction
#pragma unroll
    for (int off = 32; off > 0; off >>= 1) {
        s_inter += __shfl_down(s_inter, off, 64);
        s_match += __shfl_down(s_match, off, 64);
        s_sig   += __shfl_down(s_sig,   off, 64);
    }

    __shared__ float sh[3][4];   // 4 waves for block=256
    const int wid = tid >> 6;
    const int lid = tid & 63;
    if (lid == 0) { sh[0][wid] = s_inter; sh[1][wid] = s_match; sh[2][wid] = s_sig; }
    __syncthreads();

    if (tid == 0) {
        pI[blockIdx.x] = sh[0][0] + sh[0][1] + sh[0][2] + sh[0][3];
        pM[blockIdx.x] = sh[1][0] + sh[1][1] + sh[1][2] + sh[1][3];
        pS[blockIdx.x] = sh[2][0] + sh[2][1] + sh[2][2] + sh[2][3];
    }
}

__global__ __launch_bounds__(256) void soft_iou_final(
    const float* __restrict__ pI,
    const float* __restrict__ pM,
    const float* __restrict__ pS,
    const int* __restrict__ ncls_p,
    float* __restrict__ out,
    int g)
{
    const int tid = threadIdx.x;
    const f4_t* pI4 = (const f4_t*)pI;
    const f4_t* pM4 = (const f4_t*)pM;
    const f4_t* pS4 = (const f4_t*)pS;
    const int g4 = g >> 2;
    float si = 0.f, sm = 0.f, ss = 0.f;
    for (int i = tid; i < g4; i += 256) {
        f4_t a = pI4[i], b = pM4[i], c = pS4[i];
        si += a[0] + a[1] + a[2] + a[3];
        sm += b[0] + b[1] + b[2] + b[3];
        ss += c[0] + c[1] + c[2] + c[3];
    }
    // tail if g not multiple of 4
    for (int i = (g4 << 2) + tid; i < g; i += 256) {
        si += pI[i]; sm += pM[i]; ss += pS[i];
    }
#pragma unroll
    for (int off = 32; off > 0; off >>= 1) {
        si += __shfl_down(si, off, 64);
        sm += __shfl_down(sm, off, 64);
        ss += __shfl_down(ss, off, 64);
    }
    __shared__ float sh[3][4];
    const int wid = tid >> 6;
    const int lid = tid & 63;
    if (lid == 0) { sh[0][wid] = si; sh[1][wid] = sm; sh[2][wid] = ss; }
    __syncthreads();
    if (tid == 0) {
        float I = sh[0][0] + sh[0][1] + sh[0][2] + sh[0][3];
        float M = sh[1][0] + sh[1][1] + sh[1][2] + sh[1][3];
        float S = sh[2][0] + sh[2][1] + sh[2][2] + sh[2][3];
        float ncf = (float)(*ncls_p);
        float uni = M + (ncf + 1.f) * S - I;
        out[0] = 1.f - (I + 1.f) / (uni + 1.f);
    }
}

extern "C" void kernel_launch(void* const* d_in, const int* in_sizes, int n_in,
                              void* d_out, int out_size, void* d_ws, size_t ws_size,
                              hipStream_t stream) {
    const float* x  = (const float*)d_in[0];
    const float* t  = (const float*)d_in[1];
    const int*   nc = (const int*)d_in[2];
    float* out = (float*)d_out;
    const int n = in_sizes[0];

    // fully-resident grid; each thread loops over rounds
    long long nvec = (long long)n >> 2;
    long long threads_needed = (nvec + PAIRS - 1) / PAIRS;
    int grid = (int)((threads_needed + BLOCK - 1) / BLOCK);
    if (grid < 1) grid = 1;
    if (grid > FULLGRID) grid = FULLGRID;

    float* pI = (float*)d_ws;
    float* pM = pI + MAXGRID;
    float* pS = pM + MAXGRID;

    soft_iou_partial<<<grid, BLOCK, 0, stream>>>(x, t, nc, pI, pM, pS, n);
    soft_iou_final<<<1, 256, 0, stream>>>(pI, pM, pS, nc, out, grid);
}

// Round 3
// 253.310 us; speedup vs baseline: 1.1236x; 1.1236x over previous
//
#include <hip/hip_runtime.h>
#include <math.h>

// softIoULoss: out = 1 - (I + 1) / (M + (nc+1)*S - I + 1)
//   I = sum(sigmoid(0.5 - |x-t|) * matched)
//   M = sum(matched),  S = sum(sigmoid(0.5 - |x-t|))
//   matched = (t == floor(t)) && (t >= 0) && (t <= nc)
//
// R9 post-mortem: removing NT cost +27.5us (257.1 -> 284.6). Plain loads:
// 104us, FETCH=134MB (half L3-served!), eff read 2.58 TB/s -> the cache
// allocation path is SLOWER than NT streaming. With NT, partial ~76us =
// 3.5 TB/s read-only, invariant across ILP depth / occupancy / grid shape
// (R7/R8), and above every measured read rate on this box (fill 6.8 TB/s
// write-only, copy 2.5 TB/s total, m13 copy ~3.15 TB/s read component).
// => read-return path ceiling, we're on it. R10: revert to R8 exactly
// (restore NT). Predict bench 255-260, partial ~76us; then <<ROOFLINE>>.

#define BLOCK 256
#define PAIRS 4      // float4-pairs per thread per round
#define FULLGRID 2048   // 8 blocks/CU x 256 CU -> fully resident
#define MAXGRID 16384   // workspace partial-array spacing (ws layout fixed)

typedef float f4_t __attribute__((ext_vector_type(4)));

__device__ __forceinline__ void accum4(f4_t xv, f4_t tv, float ncf,
                                       float& s_inter, float& s_match, float& s_sig) {
#pragma unroll
    for (int j = 0; j < 4; ++j) {
        float tt = tv[j];
        float z  = 0.5f - fabsf(xv[j] - tt);
        float sg = __builtin_amdgcn_rcpf(1.0f + __expf(-z));
        float m  = (tt == floorf(tt) && tt >= 0.f && tt <= ncf) ? 1.f : 0.f;
        s_sig   += sg;
        s_match += m;
        s_inter += sg * m;
    }
}

__global__ __launch_bounds__(BLOCK, 8) void soft_iou_partial(
    const float* __restrict__ x,
    const float* __restrict__ t,
    const int* __restrict__ ncls_p,
    float* __restrict__ pI,     // [gridDim.x]
    float* __restrict__ pM,     // [gridDim.x]
    float* __restrict__ pS,     // [gridDim.x]
    int n)
{
    const int tid = threadIdx.x;
    const long long nthreads = (long long)gridDim.x * BLOCK;
    const long long gtid     = (long long)blockIdx.x * BLOCK + tid;

    const float ncf = (float)(*ncls_p);

    float s_inter = 0.f, s_match = 0.f, s_sig = 0.f;

    const long long nvec = (long long)n >> 2;   // float4 count
    const f4_t* __restrict__ x4 = (const f4_t*)x;
    const f4_t* __restrict__ t4 = (const f4_t*)t;

    const long long step = (long long)PAIRS * nthreads;
    long long i = gtid;
    // grid-stride rounds: 2*PAIRS independent NT dwordx4 loads per round,
    // x/t interleaved; NT streams past L2/L3 allocation (R9 A/B: NT is
    // +27.5us faster than plain; allocation path is the slow one).
    for (; i + (PAIRS - 1) * nthreads < nvec; i += step) {
        f4_t xv[PAIRS], tv[PAIRS];
#pragma unroll
        for (int k = 0; k < PAIRS; ++k) {
            xv[k] = __builtin_nontemporal_load(&x4[i + (long long)k * nthreads]);
            tv[k] = __builtin_nontemporal_load(&t4[i + (long long)k * nthreads]);
        }
#pragma unroll
        for (int k = 0; k < PAIRS; ++k)
            accum4(xv[k], tv[k], ncf, s_inter, s_match, s_sig);
    }
    // remaining full float4s
    for (; i < nvec; i += nthreads) {
        accum4(x4[i], t4[i], ncf, s_inter, s_match, s_sig);
    }
    // scalar tail (n % 4)
    for (long long k = (nvec << 2) + gtid; k < n; k += nthreads) {
        float tt = t[k];
        float z  = 0.5f - fabsf(x[k] - tt);
        float sg = __builtin_amdgcn_rcpf(1.0f + __expf(-z));
        float m  = (tt == floorf(tt) && tt >= 0.f && tt <= ncf) ? 1.f : 0.f;
        s_sig += sg; s_match += m; s_inter += sg * m;
    }

    // wave (64-lane) reduction
#pragma unroll
    for (int off = 32; off > 0; off >>= 1) {
        s_inter += __shfl_down(s_inter, off, 64);
        s_match += __shfl_down(s_match, off, 64);
        s_sig   += __shfl_down(s_sig,   off, 64);
    }

    __shared__ float sh[3][4];   // 4 waves for block=256
    const int wid = tid >> 6;
    const int lid = tid & 63;
    if (lid == 0) { sh[0][wid] = s_inter; sh[1][wid] = s_match; sh[2][wid] = s_sig; }
    __syncthreads();

    if (tid == 0) {
        pI[blockIdx.x] = sh[0][0] + sh[0][1] + sh[0][2] + sh[0][3];
        pM[blockIdx.x] = sh[1][0] + sh[1][1] + sh[1][2] + sh[1][3];
        pS[blockIdx.x] = sh[2][0] + sh[2][1] + sh[2][2] + sh[2][3];
    }
}

__global__ __launch_bounds__(256) void soft_iou_final(
    const float* __restrict__ pI,
    const float* __restrict__ pM,
    const float* __restrict__ pS,
    const int* __restrict__ ncls_p,
    float* __restrict__ out,
    int g)
{
    const int tid = threadIdx.x;
    const f4_t* pI4 = (const f4_t*)pI;
    const f4_t* pM4 = (const f4_t*)pM;
    const f4_t* pS4 = (const f4_t*)pS;
    const int g4 = g >> 2;
    float si = 0.f, sm = 0.f, ss = 0.f;
    for (int i = tid; i < g4; i += 256) {
        f4_t a = pI4[i], b = pM4[i], c = pS4[i];
        si += a[0] + a[1] + a[2] + a[3];
        sm += b[0] + b[1] + b[2] + b[3];
        ss += c[0] + c[1] + c[2] + c[3];
    }
    // tail if g not multiple of 4
    for (int i = (g4 << 2) + tid; i < g; i += 256) {
        si += pI[i]; sm += pM[i]; ss += pS[i];
    }
#pragma unroll
    for (int off = 32; off > 0; off >>= 1) {
        si += __shfl_down(si, off, 64);
        sm += __shfl_down(sm, off, 64);
        ss += __shfl_down(ss, off, 64);
    }
    __shared__ float sh[3][4];
    const int wid = tid >> 6;
    const int lid = tid & 63;
    if (lid == 0) { sh[0][wid] = si; sh[1][wid] = sm; sh[2][wid] = ss; }
    __syncthreads();
    if (tid == 0) {
        float I = sh[0][0] + sh[0][1] + sh[0][2] + sh[0][3];
        float M = sh[1][0] + sh[1][1] + sh[1][2] + sh[1][3];
        float S = sh[2][0] + sh[2][1] + sh[2][2] + sh[2][3];
        float ncf = (float)(*ncls_p);
        float uni = M + (ncf + 1.f) * S - I;
        out[0] = 1.f - (I + 1.f) / (uni + 1.f);
    }
}

extern "C" void kernel_launch(void* const* d_in, const int* in_sizes, int n_in,
                              void* d_out, int out_size, void* d_ws, size_t ws_size,
                              hipStream_t stream) {
    const float* x  = (const float*)d_in[0];
    const float* t  = (const float*)d_in[1];
    const int*   nc = (const int*)d_in[2];
    float* out = (float*)d_out;
    const int n = in_sizes[0];

    // fully-resident grid; each thread loops over rounds
    long long nvec = (long long)n >> 2;
    long long threads_needed = (nvec + PAIRS - 1) / PAIRS;
    int grid = (int)((threads_needed + BLOCK - 1) / BLOCK);
    if (grid < 1) grid = 1;
    if (grid > FULLGRID) grid = FULLGRID;

    float* pI = (float*)d_ws;
    float* pM = pI + MAXGRID;
    float* pS = pM + MAXGRID;

    soft_iou_partial<<<grid, BLOCK, 0, stream>>>(x, t, nc, pI, pM, pS, n);
    soft_iou_final<<<1, 256, 0, stream>>>(pI, pM, pS, nc, out, grid);
}